// Round 4
// baseline (782.091 us; speedup 1.0000x reference)
//
#include <hip/hip_runtime.h>
#include <math.h>

typedef __bf16 bf16;
typedef __bf16 bf16x8 __attribute__((ext_vector_type(8)));
typedef float floatx4 __attribute__((ext_vector_type(4)));

#define S_LEN 2048
#define BATCH 32
#define NHEAD 8
#define KC 19
#define KM 10
#define HKC 152   // 8*19
#define HKM 80    // 8*10
#define NTOT 232  // HKC + HKM
#define NPAD 256
#define ROWS 64   // rows per g12 block

// Barrier without vmcnt drain: LDS is the only cross-thread state in the
// pipelined k-loop; global loads land in private regs and stay in flight.
// (Correctness of this pattern verified in an earlier round: lgkmcnt(0)
// commits ds_writes before the barrier; compiler inserts vmcnt waits at
// the point load data is consumed.)
#define BAR() do { \
    asm volatile("s_waitcnt lgkmcnt(0)" ::: "memory"); \
    __builtin_amdgcn_s_barrier(); \
} while (0)

// ================= prep1: init + kv_proj + zeros =================
__global__ __launch_bounds__(256) void prep1(
    const int* __restrict__ em, const int* __restrict__ pmask,
    const int* __restrict__ cmask, const int* __restrict__ mmask,
    const float* __restrict__ ctab, const float* __restrict__ mtab,
    const float* __restrict__ cWk, const float* __restrict__ cbk,
    const float* __restrict__ cWv, const float* __restrict__ cbv,
    const float* __restrict__ mWk, const float* __restrict__ mbk,
    const float* __restrict__ mWv, const float* __restrict__ mbv,
    float* __restrict__ P, float* __restrict__ A2, float* __restrict__ mb,
    float* __restrict__ k1c, float* __restrict__ v1c,
    float* __restrict__ k1m, float* __restrict__ v1m,
    bf16* __restrict__ GT, bf16* __restrict__ Bt,
    float* __restrict__ c1, float* __restrict__ c2)
{
    __shared__ float smem[512];
    const int blk = blockIdx.x, tid = threadIdx.x;

    if (blk < 32) {
        int* red = (int*)smem;
        int b = blk;
        int s = 0;
        for (int i = tid; i < S_LEN; i += 256) s += em[b*S_LEN+i] * pmask[b*S_LEN+i];
        red[tid] = s; __syncthreads();
        for (int o = 128; o; o >>= 1) { if (tid < o) red[tid] += red[tid+o]; __syncthreads(); }
        if (tid == 0) P[b] = (float)red[0];
        float v = 0.f;
        if (tid < HKC) v = (float)cmask[b*KC + (tid % KC)];
        else if (tid < NTOT) v = (float)mmask[b*KM + ((tid - HKC) % KM)];
        mb[b*NPAD + tid] = v;
        A2[b*NPAD + tid] = 0.f;
    } else if (blk < 61) {
        int r = blk - 32;
        const float* T;  const float* Wk; const float* bk; const float* Wv; const float* bv;
        float* k1; float* v1; int row;
        if (r < KC) { T = ctab; Wk = cWk; bk = cbk; Wv = cWv; bv = cbv; k1 = k1c; v1 = v1c; row = r; }
        else        { T = mtab; Wk = mWk; bk = mbk; Wv = mWv; bv = mbv; k1 = k1m; v1 = v1m; row = r - KC; }
        for (int i = tid; i < 512; i += 256) smem[i] = T[row*512+i];
        __syncthreads();
        for (int j = tid; j < 512; j += 256) {
            float sk = bk[j], sv = bv[j];
            for (int d = 0; d < 512; d++) { float t = smem[d]; sk += t*Wk[d*512+j]; sv += t*Wv[d*512+j]; }
            k1[row*512+j] = sk; v1[row*512+j] = sv;
        }
    } else {
        int z = blk - 61;
        for (int i = tid; i < 16384; i += 256) GT[z*16384 + i] = (bf16)0.f;
        for (int i = tid; i < 6144; i += 256) Bt[(size_t)NTOT*1024 + z*6144 + i] = (bf16)0.f;
        if (z == 0) { c1[tid] = 0.f; c2[tid] = 0.f; }
    }
}

// ================= prep2: MqTd + W2 =================
__global__ __launch_bounds__(256) void prep2(
    const float* __restrict__ cWq, const float* __restrict__ mWq,
    const float* __restrict__ k1c, const float* __restrict__ v1c,
    const float* __restrict__ k1m, const float* __restrict__ v1m,
    const float* __restrict__ cWo, const float* __restrict__ mWo,
    float* __restrict__ MqTd, float* __restrict__ W2)
{
    __shared__ float smem[15872];
    const int blk = blockIdx.x, tid = threadIdx.x;

    if (blk < 512) {
        int D = blk;
        for (int i = tid; i < 9728; i += 256) smem[i] = k1c[i];
        for (int i = tid; i < 5120; i += 256) smem[9728+i] = k1m[i];
        for (int i = tid; i < 512; i += 256) {
            smem[14848+i] = cWq[(size_t)D*512+i];
            smem[15360+i] = mWq[(size_t)D*512+i];
        }
        __syncthreads();
        if (tid < HKC) {
            int h = tid / KC, k = tid % KC;
            const float* kr = smem + k*512 + h*64;
            float mq = 0.f;
            #pragma unroll 16
            for (int d = 0; d < 64; d++) mq += smem[14848 + h*64 + d] * kr[d];
            MqTd[D*NPAD + tid] = mq;
        }
        if (tid < HKM) {
            int h = tid / KM, k = tid % KM;
            const float* kr = smem + 9728 + k*512 + h*64;
            float mq = 0.f;
            #pragma unroll 16
            for (int d = 0; d < 64; d++) mq += smem[15360 + h*64 + d] * kr[d];
            MqTd[D*NPAD + HKC + tid] = mq;
        }
    } else {
        int n = blk - 512;
        const float* v1; const float* Wo; int h, k;
        if (n < HKC) { v1 = v1c; Wo = cWo; h = n / KC; k = n % KC; }
        else         { v1 = v1m; Wo = mWo; h = (n-HKC) / KM; k = (n-HKC) % KM; }
        if (tid < 64) smem[tid] = v1[k*512 + h*64 + tid];
        __syncthreads();
        for (int j = tid; j < 512; j += 256) {
            float s = 0.f;
            #pragma unroll 16
            for (int d = 0; d < 64; d++) s += smem[d] * Wo[(size_t)(h*64+d)*512 + j];
            W2[(size_t)n*512 + j] = s;
        }
    }
}

// ================= prep3: GT + Bt + c1/c2 =================
__global__ __launch_bounds__(256) void prep3(
    const float* __restrict__ W_lin, const float* __restrict__ b_lin,
    const float* __restrict__ MqTd, const float* __restrict__ W2,
    const float* __restrict__ k1c, const float* __restrict__ k1m,
    const float* __restrict__ cbq, const float* __restrict__ mbq,
    const float* __restrict__ cbo, const float* __restrict__ mbo,
    bf16* __restrict__ Bt, bf16* __restrict__ GT, float* __restrict__ c1, float* __restrict__ c2)
{
    __shared__ float smem[4096];
    const int blk = blockIdx.x, tid = threadIdx.x;

    if (blk < NTOT) {
        int n = blk;
        for (int i = tid; i < 512; i += 256) smem[i] = W2[(size_t)n*512 + i];
        __syncthreads();
        if (n < HKC) {
            for (int np = tid; np < HKC; np += 256) {
                float s = 0.f;
                for (int t = 0; t < 512; t++) s += smem[t] * MqTd[t*NPAD + np];
                GT[(size_t)np*NPAD + n] = (bf16)(0.125f*s);
            }
        } else {
            for (int np = tid; np < HKM; np += 256) {
                float s = 0.f;
                for (int t = 0; t < 512; t++) s += smem[t] * MqTd[t*NPAD + HKC + np];
                GT[(size_t)(HKC+np)*NPAD + n] = (bf16)(0.125f*s);
            }
        }
    } else if (blk < 360) {
        int D0 = (blk - NTOT) * 8;
        for (int i = tid; i < 4096; i += 256)
            smem[i] = W_lin[(size_t)(D0 + (i >> 9))*512 + (i & 511)];
        __syncthreads();
        if (tid < NTOT) {
            float acc[8] = {};
            for (int d = 0; d < 512; d++) {
                float m = MqTd[d*NPAD + tid];
                #pragma unroll
                for (int r = 0; r < 8; r++) acc[r] += smem[r*512 + d] * m;
            }
            #pragma unroll
            for (int r = 0; r < 8; r++)
                Bt[(size_t)tid*1024 + D0 + r] = (bf16)(0.125f*acc[r]);
        }
    } else {
        for (int i = tid; i < 512; i += 256) {
            smem[i] = b_lin[i];
            smem[512+i] = cbo[i];
            smem[1024+i] = mbo[i];
        }
        __syncthreads();
        if (tid < NTOT) {
            bool cult = tid < HKC;
            const float* bo_s = cult ? (smem+512) : (smem+1024);
            float sA = 0.f, sB = 0.f;
            for (int D = 0; D < 512; D++) {
                float m = MqTd[D*NPAD + tid];
                sA += smem[D]*m;
                sB += bo_s[D]*m;
            }
            float skq = 0.f;
            if (cult) {
                int h = tid / KC, k = tid % KC;
                for (int d = 0; d < 64; d++) skq += cbq[h*64+d] * k1c[k*512 + h*64 + d];
            } else {
                int nm = tid - HKC, h = nm / KM, k = nm % KM;
                for (int d = 0; d < 64; d++) skq += mbq[h*64+d] * k1m[k*512 + h*64 + d];
            }
            c1[tid] = 0.125f*(sA + skq);
            c2[tid] = 0.125f*(sB + skq);
        }
    }
}

// ================= g12: fused main pass, 64-row blocks, pipelined =================
// Phase-1 k-loop is software-pipelined: loads for step t+1 are issued before
// the MFMAs of step t, and both k-loop barriers are lgkm-only, so the global
// loads stay in flight across barrier + MFMA (one step of latency cover)
// instead of being drained by __syncthreads' vmcnt(0) right after issue.
__global__ __launch_bounds__(256, 3) void g12_kernel(const float* __restrict__ emb,
                                                     const bf16* __restrict__ Bt,
                                                     const bf16* __restrict__ GT,
                                                     const float* __restrict__ c1,
                                                     const float* __restrict__ c2,
                                                     const float* __restrict__ mb,
                                                     float* __restrict__ A2)
{
    __shared__ union UU {
        struct { bf16 As[ROWS*72]; bf16 Bs[256*72]; } s;   // 9216 + 36864 B
        bf16 Ls[ROWS*264];                                 // 33792 B
    } u;
    __shared__ float bias1[256], bias2[256];
    const int tid = threadIdx.x;
    const int m0 = blockIdx.x*ROWS, b = blockIdx.x >> 5;
    bias1[tid] = c1[tid] + mb[b*NPAD + tid];
    bias2[tid] = c2[tid] + mb[b*NPAD + tid];
    const int wave = tid >> 6, lane = tid & 63, lr = lane & 15, kg = lane >> 4;
    floatx4 acc[4][4] = {};
    const int arow = tid >> 2, acol = (tid & 3)*16;
    const float* ap = emb + (size_t)(m0 + arow)*1024 + acol;
    bf16* asw = u.s.As + arow*72 + acol;
    const bf16* bp = Bt + (size_t)tid*1024;
    bf16* bsw = u.s.Bs + tid*72;
    const bf16* afp = u.s.As + lr*72 + kg*8;
    const bf16* bfp = u.s.Bs + (wave*64 + lr)*72 + kg*8;

    float4 fA[4]; uint4 gB[8];
    auto LOADS = [&](int k0) {
        fA[0] = *(const float4*)(ap + k0);      fA[1] = *(const float4*)(ap + k0 + 4);
        fA[2] = *(const float4*)(ap + k0 + 8);  fA[3] = *(const float4*)(ap + k0 + 12);
        gB[0] = *(const uint4*)(bp + k0);       gB[1] = *(const uint4*)(bp + k0 + 8);
        gB[2] = *(const uint4*)(bp + k0 + 16);  gB[3] = *(const uint4*)(bp + k0 + 24);
        gB[4] = *(const uint4*)(bp + k0 + 32);  gB[5] = *(const uint4*)(bp + k0 + 40);
        gB[6] = *(const uint4*)(bp + k0 + 48);  gB[7] = *(const uint4*)(bp + k0 + 56);
    };
    auto STAGE = [&]() {
        bf16x8 p0, p1;
        p0[0]=(bf16)fA[0].x; p0[1]=(bf16)fA[0].y; p0[2]=(bf16)fA[0].z; p0[3]=(bf16)fA[0].w;
        p0[4]=(bf16)fA[1].x; p0[5]=(bf16)fA[1].y; p0[6]=(bf16)fA[1].z; p0[7]=(bf16)fA[1].w;
        p1[0]=(bf16)fA[2].x; p1[1]=(bf16)fA[2].y; p1[2]=(bf16)fA[2].z; p1[3]=(bf16)fA[2].w;
        p1[4]=(bf16)fA[3].x; p1[5]=(bf16)fA[3].y; p1[6]=(bf16)fA[3].z; p1[7]=(bf16)fA[3].w;
        *(bf16x8*)asw = p0; *(bf16x8*)(asw + 8) = p1;
        *(uint4*)bsw = gB[0]; *(uint4*)(bsw + 8) = gB[1];
        *(uint4*)(bsw + 16) = gB[2]; *(uint4*)(bsw + 24) = gB[3];
        *(uint4*)(bsw + 32) = gB[4]; *(uint4*)(bsw + 40) = gB[5];
        *(uint4*)(bsw + 48) = gB[6]; *(uint4*)(bsw + 56) = gB[7];
    };
    auto MFMA = [&]() {
        #pragma unroll
        for (int kk = 0; kk < 64; kk += 32) {
            bf16x8 af[4], bfr[4];
            #pragma unroll
            for (int mi = 0; mi < 4; mi++) af[mi] = *(const bf16x8*)(afp + mi*16*72 + kk);
            #pragma unroll
            for (int nt = 0; nt < 4; nt++) bfr[nt] = *(const bf16x8*)(bfp + nt*16*72 + kk);
            #pragma unroll
            for (int mi = 0; mi < 4; mi++)
                #pragma unroll
                for (int nt = 0; nt < 4; nt++)
                    acc[mi][nt] = __builtin_amdgcn_mfma_f32_16x16x32_bf16(af[mi], bfr[nt], acc[mi][nt], 0, 0, 0);
        }
    };

    // -------- phase 1: logits1 = emb @ Bt^T, pipelined K=64 steps --------
    LOADS(0);
    #pragma unroll 1
    for (int t = 0; t < 15; t++) {
        BAR();                // prior step's frag reads done (lgkm only)
        STAGE();              // vmcnt wait for step-t data lands here
        LOADS((t + 1)*64);    // issue next step's loads BEFORE the MFMAs
        BAR();                // stage visible (lgkm only; loads stay in flight)
        MFMA();
    }
    BAR();
    STAGE();
    BAR();
    MFMA();
    __syncthreads();
    // -------- epilogue 1: logits1 + bias -> Ls --------
    #pragma unroll
    for (int nt = 0; nt < 4; nt++) {
        int col = wave*64 + nt*16 + lr;
        float bb = bias1[col];
        #pragma unroll
        for (int mi = 0; mi < 4; mi++) {
            int row = mi*16 + kg*4;
            #pragma unroll
            for (int r = 0; r < 4; r++)
                u.Ls[(row + r)*264 + col] = (bf16)(acc[mi][nt][r] + bb);
        }
    }
    __syncthreads();
    // -------- softmax 1: 64 rows x 4 parts (per-head order unchanged) ------
    {
        int row = tid & 63, part = tid >> 6;
        bf16* Lr = u.Ls + row*264;
        if (part < 2) {
            for (int h = part*4; h < part*4 + 4; h++) {
                float lv[KC]; float m = -1e30f;
                #pragma unroll
                for (int j = 0; j < KC; j++) { lv[j] = (float)Lr[h*KC + j]; m = fmaxf(m, lv[j]); }
                float s = 0.f;
                #pragma unroll
                for (int j = 0; j < KC; j++) { lv[j] = __expf(lv[j] - m); s += lv[j]; }
                float inv = 1.f / s;
                #pragma unroll
                for (int j = 0; j < KC; j++) Lr[h*KC + j] = (bf16)(lv[j]*inv);
            }
        } else {
            for (int h = (part-2)*4; h < (part-2)*4 + 4; h++) {
                float lv[KM]; float m = -1e30f;
                #pragma unroll
                for (int j = 0; j < KM; j++) { lv[j] = (float)Lr[HKC + h*KM + j]; m = fmaxf(m, lv[j]); }
                float s = 0.f;
                #pragma unroll
                for (int j = 0; j < KM; j++) { lv[j] = __expf(lv[j] - m); s += lv[j]; }
                float inv = 1.f / s;
                #pragma unroll
                for (int j = 0; j < KM; j++) Lr[HKC + h*KM + j] = (bf16)(lv[j]*inv);
            }
            if (part == 3) for (int c = NTOT; c < NPAD; c++) Lr[c] = (bf16)0.f;
        }
    }
    __syncthreads();

    // -------- phase 3: logits2 = av1(Ls) @ GT^T, B direct from global/L2 ----
    floatx4 acc2[4][4] = {};
    {
        const bf16* afp3 = u.Ls + lr*264 + kg*8;
        const bf16* gt0 = GT + (size_t)(wave*64 + lr)*NPAD + kg*8;
        #pragma unroll 2
        for (int t = 0; t < 8; t++) {
            bf16x8 gbv[4], af3[4];
            #pragma unroll
            for (int nt = 0; nt < 4; nt++) gbv[nt] = *(const bf16x8*)(gt0 + nt*16*NPAD + t*32);
            #pragma unroll
            for (int mi = 0; mi < 4; mi++) af3[mi] = *(const bf16x8*)(afp3 + mi*16*264 + t*32);
            #pragma unroll
            for (int mi = 0; mi < 4; mi++)
                #pragma unroll
                for (int nt = 0; nt < 4; nt++)
                    acc2[mi][nt] = __builtin_amdgcn_mfma_f32_16x16x32_bf16(af3[mi], gbv[nt], acc2[mi][nt], 0, 0, 0);
        }
    }
    __syncthreads();   // all reads of av1 done before Ls is overwritten

    // -------- epilogue 2: logits2 + bias -> Ls --------
    #pragma unroll
    for (int nt = 0; nt < 4; nt++) {
        int col = wave*64 + nt*16 + lr;
        float bb = bias2[col];
        #pragma unroll
        for (int mi = 0; mi < 4; mi++) {
            int row = mi*16 + kg*4;
            #pragma unroll
            for (int r = 0; r < 4; r++)
                u.Ls[(row + r)*264 + col] = (bf16)(acc2[mi][nt][r] + bb);
        }
    }
    __syncthreads();
    // -------- softmax 2 --------
    {
        int row = tid & 63, part = tid >> 6;
        bf16* Lr = u.Ls + row*264;
        if (part < 2) {
            for (int h = part*4; h < part*4 + 4; h++) {
                float lv[KC]; float m = -1e30f;
                #pragma unroll
                for (int j = 0; j < KC; j++) { lv[j] = (float)Lr[h*KC + j]; m = fmaxf(m, lv[j]); }
                float s = 0.f;
                #pragma unroll
                for (int j = 0; j < KC; j++) { lv[j] = __expf(lv[j] - m); s += lv[j]; }
                float inv = 1.f / s;
                #pragma unroll
                for (int j = 0; j < KC; j++) Lr[h*KC + j] = (bf16)(lv[j]*inv);
            }
        } else {
            for (int h = (part-2)*4; h < (part-2)*4 + 4; h++) {
                float lv[KM]; float m = -1e30f;
                #pragma unroll
                for (int j = 0; j < KM; j++) { lv[j] = (float)Lr[HKC + h*KM + j]; m = fmaxf(m, lv[j]); }
                float s = 0.f;
                #pragma unroll
                for (int j = 0; j < KM; j++) { lv[j] = __expf(lv[j] - m); s += lv[j]; }
                float inv = 1.f / s;
                #pragma unroll
                for (int j = 0; j < KM; j++) Lr[HKC + h*KM + j] = (bf16)(lv[j]*inv);
            }
        }
    }
    __syncthreads();
    // -------- pool columns over 64 rows, accumulate into A2 --------
    {
        float s = 0.f;
        for (int r = 0; r < ROWS; r++) s += (float)u.Ls[r*264 + tid];
        if (tid < NTOT) atomicAdd(&A2[b*NPAD + tid], s);
    }
}

// ---------------- finalize ----------------
__global__ __launch_bounds__(256) void finalize_kernel(const float* __restrict__ A2, const float* __restrict__ W2,
                                                       const float* __restrict__ cbo, const float* __restrict__ mbo,
                                                       const float* __restrict__ P, float* __restrict__ out)
{
    __shared__ float a[NTOT];
    int b = blockIdx.x, tid = threadIdx.x;
    if (tid < NTOT) a[tid] = A2[b*NPAD + tid];
    __syncthreads();
    float invP = 1.f / P[b];
    for (int j = tid; j < 512; j += 256) {
        float pc = 2048.f*cbo[j], pm = 2048.f*mbo[j];
        for (int n = 0; n < HKC; n++) pc += a[n]*W2[n*512 + j];
        for (int n = HKC; n < NTOT; n++) pm += a[n]*W2[n*512 + j];
        out[b*512 + j] = pc*invP;
        out[BATCH*512 + b*512 + j] = (pc - pm)*invP;
    }
}

extern "C" void kernel_launch(void* const* d_in, const int* in_sizes, int n_in,
                              void* d_out, int out_size, void* d_ws, size_t ws_size,
                              hipStream_t stream)
{
    (void)in_sizes; (void)n_in; (void)out_size;
    const float* emb   = (const float*)d_in[0];
    const int* emask   = (const int*)d_in[1];
    const int* pmask   = (const int*)d_in[2];
    /* d_in[3] frame_mask: cancels in softmax */
    const int* cmask   = (const int*)d_in[4];
    const int* mmask   = (const int*)d_in[5];
    const float* W_lin = (const float*)d_in[6];
    const float* b_lin = (const float*)d_in[7];
    const float* ctab  = (const float*)d_in[8];
    const float* mtab  = (const float*)d_in[9];
    const float* cWq = (const float*)d_in[10]; const float* cbq = (const float*)d_in[11];
    const float* cWk = (const float*)d_in[12]; const float* cbk = (const float*)d_in[13];
    const float* cWv = (const float*)d_in[14]; const float* cbv = (const float*)d_in[15];
    const float* cWo = (const float*)d_in[16]; const float* cbo = (const float*)d_in[17];
    const float* mWq = (const float*)d_in[18]; const float* mbq = (const float*)d_in[19];
    const float* mWk = (const float*)d_in[20]; const float* mbk = (const float*)d_in[21];
    const float* mWv = (const float*)d_in[22]; const float* mbv = (const float*)d_in[23];
    const float* mWo = (const float*)d_in[24]; const float* mbo = (const float*)d_in[25];
    float* outp = (float*)d_out;

    if (ws_size < 40000000UL) return;

    char* ws = (char*)d_ws;
    size_t o = 0;
    bf16* Bt    = (bf16*)(ws + o); o += 256*1024*2;
    bf16* GT    = (bf16*)(ws + o); o += NPAD*NPAD*2;
    float* k1c  = (float*)(ws + o); o += KC*512*4;
    float* v1c  = (float*)(ws + o); o += KC*512*4;
    float* k1m  = (float*)(ws + o); o += KM*512*4;
    float* v1m  = (float*)(ws + o); o += KM*512*4;
    float* MqTd = (float*)(ws + o); o += (size_t)512*NPAD*4;
    float* W2   = (float*)(ws + o); o += (size_t)NTOT*512*4;
    float* c1   = (float*)(ws + o); o += NPAD*4;
    float* c2   = (float*)(ws + o); o += NPAD*4;
    float* mbt  = (float*)(ws + o); o += BATCH*NPAD*4;
    float* P    = (float*)(ws + o); o += 128;
    float* A2   = (float*)(ws + o); o += BATCH*NPAD*4;

    dim3 blk(256);

    prep1<<<dim3(65), blk, 0, stream>>>(emask, pmask, cmask, mmask, ctab, mtab,
                                        cWk, cbk, cWv, cbv, mWk, mbk, mWv, mbv,
                                        P, A2, mbt, k1c, v1c, k1m, v1m, GT, Bt, c1, c2);
    prep2<<<dim3(744), blk, 0, stream>>>(cWq, mWq, k1c, v1c, k1m, v1m, cWo, mWo, MqTd, W2);
    prep3<<<dim3(361), blk, 0, stream>>>(W_lin, b_lin, MqTd, W2, k1c, k1m,
                                         cbq, mbq, cbo, mbo, Bt, GT, c1, c2);
    g12_kernel<<<dim3(1024), blk, 0, stream>>>(emb, Bt, GT, c1, c2, mbt, A2);
    finalize_kernel<<<dim3(BATCH), blk, 0, stream>>>(A2, W2, cbo, mbo, P, outp);
}

// Round 5
// 633.524 us; speedup vs baseline: 1.2345x; 1.2345x over previous
//
#include <hip/hip_runtime.h>
#include <math.h>

typedef __bf16 bf16;
typedef __bf16 bf16x8 __attribute__((ext_vector_type(8)));
typedef float floatx4 __attribute__((ext_vector_type(4)));

#define S_LEN 2048
#define BATCH 32
#define NHEAD 8
#define KC 19
#define KM 10
#define HKC 152   // 8*19
#define HKM 80    // 8*10
#define NTOT 232  // HKC + HKM
#define NPAD 256
#define ROWS 64   // rows per g12 block

// ================= prep1: init + kv_proj + zeros =================
__global__ __launch_bounds__(256) void prep1(
    const int* __restrict__ em, const int* __restrict__ pmask,
    const int* __restrict__ cmask, const int* __restrict__ mmask,
    const float* __restrict__ ctab, const float* __restrict__ mtab,
    const float* __restrict__ cWk, const float* __restrict__ cbk,
    const float* __restrict__ cWv, const float* __restrict__ cbv,
    const float* __restrict__ mWk, const float* __restrict__ mbk,
    const float* __restrict__ mWv, const float* __restrict__ mbv,
    float* __restrict__ P, float* __restrict__ A2, float* __restrict__ mb,
    float* __restrict__ k1c, float* __restrict__ v1c,
    float* __restrict__ k1m, float* __restrict__ v1m,
    bf16* __restrict__ GT, bf16* __restrict__ Bt,
    float* __restrict__ c1, float* __restrict__ c2)
{
    __shared__ float smem[512];
    const int blk = blockIdx.x, tid = threadIdx.x;

    if (blk < 32) {
        int* red = (int*)smem;
        int b = blk;
        int s = 0;
        for (int i = tid; i < S_LEN; i += 256) s += em[b*S_LEN+i] * pmask[b*S_LEN+i];
        red[tid] = s; __syncthreads();
        for (int o = 128; o; o >>= 1) { if (tid < o) red[tid] += red[tid+o]; __syncthreads(); }
        if (tid == 0) P[b] = (float)red[0];
        float v = 0.f;
        if (tid < HKC) v = (float)cmask[b*KC + (tid % KC)];
        else if (tid < NTOT) v = (float)mmask[b*KM + ((tid - HKC) % KM)];
        mb[b*NPAD + tid] = v;
        A2[b*NPAD + tid] = 0.f;
    } else if (blk < 61) {
        int r = blk - 32;
        const float* T;  const float* Wk; const float* bk; const float* Wv; const float* bv;
        float* k1; float* v1; int row;
        if (r < KC) { T = ctab; Wk = cWk; bk = cbk; Wv = cWv; bv = cbv; k1 = k1c; v1 = v1c; row = r; }
        else        { T = mtab; Wk = mWk; bk = mbk; Wv = mWv; bv = mbv; k1 = k1m; v1 = v1m; row = r - KC; }
        for (int i = tid; i < 512; i += 256) smem[i] = T[row*512+i];
        __syncthreads();
        for (int j = tid; j < 512; j += 256) {
            float sk = bk[j], sv = bv[j];
            for (int d = 0; d < 512; d++) { float t = smem[d]; sk += t*Wk[d*512+j]; sv += t*Wv[d*512+j]; }
            k1[row*512+j] = sk; v1[row*512+j] = sv;
        }
    } else {
        int z = blk - 61;
        for (int i = tid; i < 16384; i += 256) GT[z*16384 + i] = (bf16)0.f;
        for (int i = tid; i < 6144; i += 256) Bt[(size_t)NTOT*1024 + z*6144 + i] = (bf16)0.f;
        if (z == 0) { c1[tid] = 0.f; c2[tid] = 0.f; }
    }
}

// ================= prep2: MqTd + W2 =================
__global__ __launch_bounds__(256) void prep2(
    const float* __restrict__ cWq, const float* __restrict__ mWq,
    const float* __restrict__ k1c, const float* __restrict__ v1c,
    const float* __restrict__ k1m, const float* __restrict__ v1m,
    const float* __restrict__ cWo, const float* __restrict__ mWo,
    float* __restrict__ MqTd, float* __restrict__ W2)
{
    __shared__ float smem[15872];
    const int blk = blockIdx.x, tid = threadIdx.x;

    if (blk < 512) {
        int D = blk;
        for (int i = tid; i < 9728; i += 256) smem[i] = k1c[i];
        for (int i = tid; i < 5120; i += 256) smem[9728+i] = k1m[i];
        for (int i = tid; i < 512; i += 256) {
            smem[14848+i] = cWq[(size_t)D*512+i];
            smem[15360+i] = mWq[(size_t)D*512+i];
        }
        __syncthreads();
        if (tid < HKC) {
            int h = tid / KC, k = tid % KC;
            const float* kr = smem + k*512 + h*64;
            float mq = 0.f;
            #pragma unroll 16
            for (int d = 0; d < 64; d++) mq += smem[14848 + h*64 + d] * kr[d];
            MqTd[D*NPAD + tid] = mq;
        }
        if (tid < HKM) {
            int h = tid / KM, k = tid % KM;
            const float* kr = smem + 9728 + k*512 + h*64;
            float mq = 0.f;
            #pragma unroll 16
            for (int d = 0; d < 64; d++) mq += smem[15360 + h*64 + d] * kr[d];
            MqTd[D*NPAD + HKC + tid] = mq;
        }
    } else {
        int n = blk - 512;
        const float* v1; const float* Wo; int h, k;
        if (n < HKC) { v1 = v1c; Wo = cWo; h = n / KC; k = n % KC; }
        else         { v1 = v1m; Wo = mWo; h = (n-HKC) / KM; k = (n-HKC) % KM; }
        if (tid < 64) smem[tid] = v1[k*512 + h*64 + tid];
        __syncthreads();
        for (int j = tid; j < 512; j += 256) {
            float s = 0.f;
            #pragma unroll 16
            for (int d = 0; d < 64; d++) s += smem[d] * Wo[(size_t)(h*64+d)*512 + j];
            W2[(size_t)n*512 + j] = s;
        }
    }
}

// ================= prep3: GT + Bt + c1/c2 =================
__global__ __launch_bounds__(256) void prep3(
    const float* __restrict__ W_lin, const float* __restrict__ b_lin,
    const float* __restrict__ MqTd, const float* __restrict__ W2,
    const float* __restrict__ k1c, const float* __restrict__ k1m,
    const float* __restrict__ cbq, const float* __restrict__ mbq,
    const float* __restrict__ cbo, const float* __restrict__ mbo,
    bf16* __restrict__ Bt, bf16* __restrict__ GT, float* __restrict__ c1, float* __restrict__ c2)
{
    __shared__ float smem[4096];
    const int blk = blockIdx.x, tid = threadIdx.x;

    if (blk < NTOT) {
        int n = blk;
        for (int i = tid; i < 512; i += 256) smem[i] = W2[(size_t)n*512 + i];
        __syncthreads();
        if (n < HKC) {
            for (int np = tid; np < HKC; np += 256) {
                float s = 0.f;
                for (int t = 0; t < 512; t++) s += smem[t] * MqTd[t*NPAD + np];
                GT[(size_t)np*NPAD + n] = (bf16)(0.125f*s);
            }
        } else {
            for (int np = tid; np < HKM; np += 256) {
                float s = 0.f;
                for (int t = 0; t < 512; t++) s += smem[t] * MqTd[t*NPAD + HKC + np];
                GT[(size_t)(HKC+np)*NPAD + n] = (bf16)(0.125f*s);
            }
        }
    } else if (blk < 360) {
        int D0 = (blk - NTOT) * 8;
        for (int i = tid; i < 4096; i += 256)
            smem[i] = W_lin[(size_t)(D0 + (i >> 9))*512 + (i & 511)];
        __syncthreads();
        if (tid < NTOT) {
            float acc[8] = {};
            for (int d = 0; d < 512; d++) {
                float m = MqTd[d*NPAD + tid];
                #pragma unroll
                for (int r = 0; r < 8; r++) acc[r] += smem[r*512 + d] * m;
            }
            #pragma unroll
            for (int r = 0; r < 8; r++)
                Bt[(size_t)tid*1024 + D0 + r] = (bf16)(0.125f*acc[r]);
        }
    } else {
        for (int i = tid; i < 512; i += 256) {
            smem[i] = b_lin[i];
            smem[512+i] = cbo[i];
            smem[1024+i] = mbo[i];
        }
        __syncthreads();
        if (tid < NTOT) {
            bool cult = tid < HKC;
            const float* bo_s = cult ? (smem+512) : (smem+1024);
            float sA = 0.f, sB = 0.f;
            for (int D = 0; D < 512; D++) {
                float m = MqTd[D*NPAD + tid];
                sA += smem[D]*m;
                sB += bo_s[D]*m;
            }
            float skq = 0.f;
            if (cult) {
                int h = tid / KC, k = tid % KC;
                for (int d = 0; d < 64; d++) skq += cbq[h*64+d] * k1c[k*512 + h*64 + d];
            } else {
                int nm = tid - HKC, h = nm / KM, k = nm % KM;
                for (int d = 0; d < 64; d++) skq += mbq[h*64+d] * k1m[k*512 + h*64 + d];
            }
            c1[tid] = 0.125f*(sA + skq);
            c2[tid] = 0.125f*(sB + skq);
        }
    }
}

// ================= g12: fused main pass, 64-row blocks, inline pipeline =====
// Phase-1 k-loop software-pipelined with lgkm-only barriers. Staging data
// lives in individually-named SCALAR locals (SSA values, never addressable)
// so the asm "memory" clobbers cannot demote them to scratch (the round-4
// failure mode: lambda capture-by-ref + memory clobber -> 253 MB scratch).
__global__ __launch_bounds__(256, 3) void g12_kernel(const float* __restrict__ emb,
                                                     const bf16* __restrict__ Bt,
                                                     const bf16* __restrict__ GT,
                                                     const float* __restrict__ c1,
                                                     const float* __restrict__ c2,
                                                     const float* __restrict__ mb,
                                                     float* __restrict__ A2)
{
    __shared__ union UU {
        struct { bf16 As[ROWS*72]; bf16 Bs[256*72]; } s;   // 9216 + 36864 B
        bf16 Ls[ROWS*264];                                 // 33792 B
    } u;
    __shared__ float bias1[256], bias2[256];
    const int tid = threadIdx.x;
    const int m0 = blockIdx.x*ROWS, b = blockIdx.x >> 5;
    bias1[tid] = c1[tid] + mb[b*NPAD + tid];
    bias2[tid] = c2[tid] + mb[b*NPAD + tid];
    const int wave = tid >> 6, lane = tid & 63, lr = lane & 15, kg = lane >> 4;
    floatx4 acc[4][4] = {};
    const int arow = tid >> 2, acol = (tid & 3)*16;
    const float* ap = emb + (size_t)(m0 + arow)*1024 + acol;
    bf16* asw = u.s.As + arow*72 + acol;
    const bf16* bp = Bt + (size_t)tid*1024;
    bf16* bsw = u.s.Bs + tid*72;
    const bf16* afp = u.s.As + lr*72 + kg*8;
    const bf16* bfp = u.s.Bs + (wave*64 + lr)*72 + kg*8;

    // -------- phase 1: logits1 = emb @ Bt^T, pipelined K=64 steps --------
    float4 f0, f1, f2, f3;
    uint4 q0, q1, q2, q3, q4, q5, q6, q7;
    f0 = *(const float4*)(ap);      f1 = *(const float4*)(ap + 4);
    f2 = *(const float4*)(ap + 8);  f3 = *(const float4*)(ap + 12);
    q0 = *(const uint4*)(bp);       q1 = *(const uint4*)(bp + 8);
    q2 = *(const uint4*)(bp + 16);  q3 = *(const uint4*)(bp + 24);
    q4 = *(const uint4*)(bp + 32);  q5 = *(const uint4*)(bp + 40);
    q6 = *(const uint4*)(bp + 48);  q7 = *(const uint4*)(bp + 56);
    #pragma unroll 1
    for (int t = 0; t < 16; t++) {
        asm volatile("s_waitcnt lgkmcnt(0)" ::: "memory");
        __builtin_amdgcn_s_barrier();          // prev frag reads done; LDS reusable
        // STAGE step t (compiler inserts vmcnt waits here -- one iter after issue)
        {
            bf16x8 p0, p1;
            p0[0]=(bf16)f0.x; p0[1]=(bf16)f0.y; p0[2]=(bf16)f0.z; p0[3]=(bf16)f0.w;
            p0[4]=(bf16)f1.x; p0[5]=(bf16)f1.y; p0[6]=(bf16)f1.z; p0[7]=(bf16)f1.w;
            p1[0]=(bf16)f2.x; p1[1]=(bf16)f2.y; p1[2]=(bf16)f2.z; p1[3]=(bf16)f2.w;
            p1[4]=(bf16)f3.x; p1[5]=(bf16)f3.y; p1[6]=(bf16)f3.z; p1[7]=(bf16)f3.w;
            *(bf16x8*)asw = p0; *(bf16x8*)(asw + 8) = p1;
            *(uint4*)bsw = q0;        *(uint4*)(bsw + 8) = q1;
            *(uint4*)(bsw + 16) = q2; *(uint4*)(bsw + 24) = q3;
            *(uint4*)(bsw + 32) = q4; *(uint4*)(bsw + 40) = q5;
            *(uint4*)(bsw + 48) = q6; *(uint4*)(bsw + 56) = q7;
        }
        // issue loads for step t+1 (stay in flight across barrier + MFMAs)
        if (t < 15) {
            const float* a2 = ap + (t + 1)*64;
            const bf16*  b2 = bp + (t + 1)*64;
            f0 = *(const float4*)(a2);      f1 = *(const float4*)(a2 + 4);
            f2 = *(const float4*)(a2 + 8);  f3 = *(const float4*)(a2 + 12);
            q0 = *(const uint4*)(b2);       q1 = *(const uint4*)(b2 + 8);
            q2 = *(const uint4*)(b2 + 16);  q3 = *(const uint4*)(b2 + 24);
            q4 = *(const uint4*)(b2 + 32);  q5 = *(const uint4*)(b2 + 40);
            q6 = *(const uint4*)(b2 + 48);  q7 = *(const uint4*)(b2 + 56);
        }
        asm volatile("s_waitcnt lgkmcnt(0)" ::: "memory");
        __builtin_amdgcn_s_barrier();          // staged tile visible
        #pragma unroll
        for (int kk = 0; kk < 64; kk += 32) {
            bf16x8 af[4], bfr[4];
            #pragma unroll
            for (int mi = 0; mi < 4; mi++) af[mi] = *(const bf16x8*)(afp + mi*16*72 + kk);
            #pragma unroll
            for (int nt = 0; nt < 4; nt++) bfr[nt] = *(const bf16x8*)(bfp + nt*16*72 + kk);
            #pragma unroll
            for (int mi = 0; mi < 4; mi++)
                #pragma unroll
                for (int nt = 0; nt < 4; nt++)
                    acc[mi][nt] = __builtin_amdgcn_mfma_f32_16x16x32_bf16(af[mi], bfr[nt], acc[mi][nt], 0, 0, 0);
        }
    }
    __syncthreads();
    // -------- epilogue 1: logits1 + bias -> Ls --------
    #pragma unroll
    for (int nt = 0; nt < 4; nt++) {
        int col = wave*64 + nt*16 + lr;
        float bb = bias1[col];
        #pragma unroll
        for (int mi = 0; mi < 4; mi++) {
            int row = mi*16 + kg*4;
            #pragma unroll
            for (int r = 0; r < 4; r++)
                u.Ls[(row + r)*264 + col] = (bf16)(acc[mi][nt][r] + bb);
        }
    }
    __syncthreads();
    // -------- softmax 1: 64 rows x 4 parts (per-head order unchanged) ------
    {
        int row = tid & 63, part = tid >> 6;
        bf16* Lr = u.Ls + row*264;
        if (part < 2) {
            for (int h = part*4; h < part*4 + 4; h++) {
                float lv[KC]; float m = -1e30f;
                #pragma unroll
                for (int j = 0; j < KC; j++) { lv[j] = (float)Lr[h*KC + j]; m = fmaxf(m, lv[j]); }
                float s = 0.f;
                #pragma unroll
                for (int j = 0; j < KC; j++) { lv[j] = __expf(lv[j] - m); s += lv[j]; }
                float inv = 1.f / s;
                #pragma unroll
                for (int j = 0; j < KC; j++) Lr[h*KC + j] = (bf16)(lv[j]*inv);
            }
        } else {
            for (int h = (part-2)*4; h < (part-2)*4 + 4; h++) {
                float lv[KM]; float m = -1e30f;
                #pragma unroll
                for (int j = 0; j < KM; j++) { lv[j] = (float)Lr[HKC + h*KM + j]; m = fmaxf(m, lv[j]); }
                float s = 0.f;
                #pragma unroll
                for (int j = 0; j < KM; j++) { lv[j] = __expf(lv[j] - m); s += lv[j]; }
                float inv = 1.f / s;
                #pragma unroll
                for (int j = 0; j < KM; j++) Lr[HKC + h*KM + j] = (bf16)(lv[j]*inv);
            }
            if (part == 3) for (int c = NTOT; c < NPAD; c++) Lr[c] = (bf16)0.f;
        }
    }
    __syncthreads();

    // -------- phase 3: logits2 = av1(Ls) @ GT^T, B direct from global/L2 ----
    floatx4 acc2[4][4] = {};
    {
        const bf16* afp3 = u.Ls + lr*264 + kg*8;
        const bf16* gt0 = GT + (size_t)(wave*64 + lr)*NPAD + kg*8;
        #pragma unroll 2
        for (int t = 0; t < 8; t++) {
            bf16x8 gbv[4], af3[4];
            #pragma unroll
            for (int nt = 0; nt < 4; nt++) gbv[nt] = *(const bf16x8*)(gt0 + nt*16*NPAD + t*32);
            #pragma unroll
            for (int mi = 0; mi < 4; mi++) af3[mi] = *(const bf16x8*)(afp3 + mi*16*264 + t*32);
            #pragma unroll
            for (int mi = 0; mi < 4; mi++)
                #pragma unroll
                for (int nt = 0; nt < 4; nt++)
                    acc2[mi][nt] = __builtin_amdgcn_mfma_f32_16x16x32_bf16(af3[mi], gbv[nt], acc2[mi][nt], 0, 0, 0);
        }
    }
    __syncthreads();   // all reads of av1 done before Ls is overwritten

    // -------- epilogue 2: logits2 + bias -> Ls --------
    #pragma unroll
    for (int nt = 0; nt < 4; nt++) {
        int col = wave*64 + nt*16 + lr;
        float bb = bias2[col];
        #pragma unroll
        for (int mi = 0; mi < 4; mi++) {
            int row = mi*16 + kg*4;
            #pragma unroll
            for (int r = 0; r < 4; r++)
                u.Ls[(row + r)*264 + col] = (bf16)(acc2[mi][nt][r] + bb);
        }
    }
    __syncthreads();
    // -------- softmax 2 --------
    {
        int row = tid & 63, part = tid >> 6;
        bf16* Lr = u.Ls + row*264;
        if (part < 2) {
            for (int h = part*4; h < part*4 + 4; h++) {
                float lv[KC]; float m = -1e30f;
                #pragma unroll
                for (int j = 0; j < KC; j++) { lv[j] = (float)Lr[h*KC + j]; m = fmaxf(m, lv[j]); }
                float s = 0.f;
                #pragma unroll
                for (int j = 0; j < KC; j++) { lv[j] = __expf(lv[j] - m); s += lv[j]; }
                float inv = 1.f / s;
                #pragma unroll
                for (int j = 0; j < KC; j++) Lr[h*KC + j] = (bf16)(lv[j]*inv);
            }
        } else {
            for (int h = (part-2)*4; h < (part-2)*4 + 4; h++) {
                float lv[KM]; float m = -1e30f;
                #pragma unroll
                for (int j = 0; j < KM; j++) { lv[j] = (float)Lr[HKC + h*KM + j]; m = fmaxf(m, lv[j]); }
                float s = 0.f;
                #pragma unroll
                for (int j = 0; j < KM; j++) { lv[j] = __expf(lv[j] - m); s += lv[j]; }
                float inv = 1.f / s;
                #pragma unroll
                for (int j = 0; j < KM; j++) Lr[HKC + h*KM + j] = (bf16)(lv[j]*inv);
            }
        }
    }
    __syncthreads();
    // -------- pool columns over 64 rows, accumulate into A2 --------
    {
        float s = 0.f;
        for (int r = 0; r < ROWS; r++) s += (float)u.Ls[r*264 + tid];
        if (tid < NTOT) atomicAdd(&A2[b*NPAD + tid], s);
    }
}

// ---------------- finalize ----------------
__global__ __launch_bounds__(256) void finalize_kernel(const float* __restrict__ A2, const float* __restrict__ W2,
                                                       const float* __restrict__ cbo, const float* __restrict__ mbo,
                                                       const float* __restrict__ P, float* __restrict__ out)
{
    __shared__ float a[NTOT];
    int b = blockIdx.x, tid = threadIdx.x;
    if (tid < NTOT) a[tid] = A2[b*NPAD + tid];
    __syncthreads();
    float invP = 1.f / P[b];
    for (int j = tid; j < 512; j += 256) {
        float pc = 2048.f*cbo[j], pm = 2048.f*mbo[j];
        for (int n = 0; n < HKC; n++) pc += a[n]*W2[n*512 + j];
        for (int n = HKC; n < NTOT; n++) pm += a[n]*W2[n*512 + j];
        out[b*512 + j] = pc*invP;
        out[BATCH*512 + b*512 + j] = (pc - pm)*invP;
    }
}

extern "C" void kernel_launch(void* const* d_in, const int* in_sizes, int n_in,
                              void* d_out, int out_size, void* d_ws, size_t ws_size,
                              hipStream_t stream)
{
    (void)in_sizes; (void)n_in; (void)out_size;
    const float* emb   = (const float*)d_in[0];
    const int* emask   = (const int*)d_in[1];
    const int* pmask   = (const int*)d_in[2];
    /* d_in[3] frame_mask: cancels in softmax */
    const int* cmask   = (const int*)d_in[4];
    const int* mmask   = (const int*)d_in[5];
    const float* W_lin = (const float*)d_in[6];
    const float* b_lin = (const float*)d_in[7];
    const float* ctab  = (const float*)d_in[8];
    const float* mtab  = (const float*)d_in[9];
    const float* cWq = (const float*)d_in[10]; const float* cbq = (const float*)d_in[11];
    const float* cWk = (const float*)d_in[12]; const float* cbk = (const float*)d_in[13];
    const float* cWv = (const float*)d_in[14]; const float* cbv = (const float*)d_in[15];
    const float* cWo = (const float*)d_in[16]; const float* cbo = (const float*)d_in[17];
    const float* mWq = (const float*)d_in[18]; const float* mbq = (const float*)d_in[19];
    const float* mWk = (const float*)d_in[20]; const float* mbk = (const float*)d_in[21];
    const float* mWv = (const float*)d_in[22]; const float* mbv = (const float*)d_in[23];
    const float* mWo = (const float*)d_in[24]; const float* mbo = (const float*)d_in[25];
    float* outp = (float*)d_out;

    if (ws_size < 40000000UL) return;

    char* ws = (char*)d_ws;
    size_t o = 0;
    bf16* Bt    = (bf16*)(ws + o); o += 256*1024*2;
    bf16* GT    = (bf16*)(ws + o); o += NPAD*NPAD*2;
    float* k1c  = (float*)(ws + o); o += KC*512*4;
    float* v1c  = (float*)(ws + o); o += KC*512*4;
    float* k1m  = (float*)(ws + o); o += KM*512*4;
    float* v1m  = (float*)(ws + o); o += KM*512*4;
    float* MqTd = (float*)(ws + o); o += (size_t)512*NPAD*4;
    float* W2   = (float*)(ws + o); o += (size_t)NTOT*512*4;
    float* c1   = (float*)(ws + o); o += NPAD*4;
    float* c2   = (float*)(ws + o); o += NPAD*4;
    float* mbt  = (float*)(ws + o); o += BATCH*NPAD*4;
    float* P    = (float*)(ws + o); o += 128;
    float* A2   = (float*)(ws + o); o += BATCH*NPAD*4;

    dim3 blk(256);

    prep1<<<dim3(65), blk, 0, stream>>>(emask, pmask, cmask, mmask, ctab, mtab,
                                        cWk, cbk, cWv, cbv, mWk, mbk, mWv, mbv,
                                        P, A2, mbt, k1c, v1c, k1m, v1m, GT, Bt, c1, c2);
    prep2<<<dim3(744), blk, 0, stream>>>(cWq, mWq, k1c, v1c, k1m, v1m, cWo, mWo, MqTd, W2);
    prep3<<<dim3(361), blk, 0, stream>>>(W_lin, b_lin, MqTd, W2, k1c, k1m,
                                         cbq, mbq, cbo, mbo, Bt, GT, c1, c2);
    g12_kernel<<<dim3(1024), blk, 0, stream>>>(emb, Bt, GT, c1, c2, mbt, A2);
    finalize_kernel<<<dim3(BATCH), blk, 0, stream>>>(A2, W2, cbo, mbo, P, outp);
}

// Round 6
// 602.856 us; speedup vs baseline: 1.2973x; 1.0509x over previous
//
#include <hip/hip_runtime.h>
#include <math.h>

typedef __bf16 bf16;
typedef __bf16 bf16x8 __attribute__((ext_vector_type(8)));
typedef float floatx4 __attribute__((ext_vector_type(4)));

#define S_LEN 2048
#define BATCH 32
#define NHEAD 8
#define KC 19
#define KM 10
#define HKC 152   // 8*19
#define HKM 80    // 8*10
#define NTOT 232  // HKC + HKM
#define NPAD 256
#define ROWS 64   // rows per g12 block

// Bt layout is K-tiled: Bt[(step*256 + n)*64 + kk] holds B[n][step*64+kk],
// so each g12 staging step reads one contiguous 32 KB block (coalesced
// wave-contiguous loads: 16 cache lines/instr instead of 64 -- the round-5
// bottleneck was per-lane 2KB-stride loads serializing address processing).

// ================= prep1: init + kv_proj + zeros =================
__global__ __launch_bounds__(256) void prep1(
    const int* __restrict__ em, const int* __restrict__ pmask,
    const int* __restrict__ cmask, const int* __restrict__ mmask,
    const float* __restrict__ ctab, const float* __restrict__ mtab,
    const float* __restrict__ cWk, const float* __restrict__ cbk,
    const float* __restrict__ cWv, const float* __restrict__ cbv,
    const float* __restrict__ mWk, const float* __restrict__ mbk,
    const float* __restrict__ mWv, const float* __restrict__ mbv,
    float* __restrict__ P, float* __restrict__ A2, float* __restrict__ mb,
    float* __restrict__ k1c, float* __restrict__ v1c,
    float* __restrict__ k1m, float* __restrict__ v1m,
    bf16* __restrict__ GT, bf16* __restrict__ Bt,
    float* __restrict__ c1, float* __restrict__ c2)
{
    __shared__ float smem[512];
    const int blk = blockIdx.x, tid = threadIdx.x;

    if (blk < 32) {
        int* red = (int*)smem;
        int b = blk;
        int s = 0;
        for (int i = tid; i < S_LEN; i += 256) s += em[b*S_LEN+i] * pmask[b*S_LEN+i];
        red[tid] = s; __syncthreads();
        for (int o = 128; o; o >>= 1) { if (tid < o) red[tid] += red[tid+o]; __syncthreads(); }
        if (tid == 0) P[b] = (float)red[0];
        float v = 0.f;
        if (tid < HKC) v = (float)cmask[b*KC + (tid % KC)];
        else if (tid < NTOT) v = (float)mmask[b*KM + ((tid - HKC) % KM)];
        mb[b*NPAD + tid] = v;
        A2[b*NPAD + tid] = 0.f;
    } else if (blk < 61) {
        int r = blk - 32;
        const float* T;  const float* Wk; const float* bk; const float* Wv; const float* bv;
        float* k1; float* v1; int row;
        if (r < KC) { T = ctab; Wk = cWk; bk = cbk; Wv = cWv; bv = cbv; k1 = k1c; v1 = v1c; row = r; }
        else        { T = mtab; Wk = mWk; bk = mbk; Wv = mWv; bv = mbv; k1 = k1m; v1 = v1m; row = r - KC; }
        for (int i = tid; i < 512; i += 256) smem[i] = T[row*512+i];
        __syncthreads();
        for (int j = tid; j < 512; j += 256) {
            float sk = bk[j], sv = bv[j];
            for (int d = 0; d < 512; d++) { float t = smem[d]; sk += t*Wk[d*512+j]; sv += t*Wv[d*512+j]; }
            k1[row*512+j] = sk; v1[row*512+j] = sv;
        }
    } else {
        int z = blk - 61;
        for (int i = tid; i < 16384; i += 256) GT[z*16384 + i] = (bf16)0.f;
        // zero pad rows 232..255 of the K-tiled Bt: steps z*4 .. z*4+3,
        // each step's pad = 24 rows * 64 = 1536 contiguous elements.
        for (int i = tid; i < 6144; i += 256) {
            int t = z*4 + (i / 1536);
            int j = i % 1536;
            Bt[(size_t)(t*256 + NTOT)*64 + j] = (bf16)0.f;
        }
        if (z == 0) { c1[tid] = 0.f; c2[tid] = 0.f; }
    }
}

// ================= prep2: MqTd + W2 =================
__global__ __launch_bounds__(256) void prep2(
    const float* __restrict__ cWq, const float* __restrict__ mWq,
    const float* __restrict__ k1c, const float* __restrict__ v1c,
    const float* __restrict__ k1m, const float* __restrict__ v1m,
    const float* __restrict__ cWo, const float* __restrict__ mWo,
    float* __restrict__ MqTd, float* __restrict__ W2)
{
    __shared__ float smem[15872];
    const int blk = blockIdx.x, tid = threadIdx.x;

    if (blk < 512) {
        int D = blk;
        for (int i = tid; i < 9728; i += 256) smem[i] = k1c[i];
        for (int i = tid; i < 5120; i += 256) smem[9728+i] = k1m[i];
        for (int i = tid; i < 512; i += 256) {
            smem[14848+i] = cWq[(size_t)D*512+i];
            smem[15360+i] = mWq[(size_t)D*512+i];
        }
        __syncthreads();
        if (tid < HKC) {
            int h = tid / KC, k = tid % KC;
            const float* kr = smem + k*512 + h*64;
            float mq = 0.f;
            #pragma unroll 16
            for (int d = 0; d < 64; d++) mq += smem[14848 + h*64 + d] * kr[d];
            MqTd[D*NPAD + tid] = mq;
        }
        if (tid < HKM) {
            int h = tid / KM, k = tid % KM;
            const float* kr = smem + 9728 + k*512 + h*64;
            float mq = 0.f;
            #pragma unroll 16
            for (int d = 0; d < 64; d++) mq += smem[15360 + h*64 + d] * kr[d];
            MqTd[D*NPAD + HKC + tid] = mq;
        }
    } else {
        int n = blk - 512;
        const float* v1; const float* Wo; int h, k;
        if (n < HKC) { v1 = v1c; Wo = cWo; h = n / KC; k = n % KC; }
        else         { v1 = v1m; Wo = mWo; h = (n-HKC) / KM; k = (n-HKC) % KM; }
        if (tid < 64) smem[tid] = v1[k*512 + h*64 + tid];
        __syncthreads();
        for (int j = tid; j < 512; j += 256) {
            float s = 0.f;
            #pragma unroll 16
            for (int d = 0; d < 64; d++) s += smem[d] * Wo[(size_t)(h*64+d)*512 + j];
            W2[(size_t)n*512 + j] = s;
        }
    }
}

// ================= prep3: GT + Bt + c1/c2 =================
__global__ __launch_bounds__(256) void prep3(
    const float* __restrict__ W_lin, const float* __restrict__ b_lin,
    const float* __restrict__ MqTd, const float* __restrict__ W2,
    const float* __restrict__ k1c, const float* __restrict__ k1m,
    const float* __restrict__ cbq, const float* __restrict__ mbq,
    const float* __restrict__ cbo, const float* __restrict__ mbo,
    bf16* __restrict__ Bt, bf16* __restrict__ GT, float* __restrict__ c1, float* __restrict__ c2)
{
    __shared__ float smem[4096];
    const int blk = blockIdx.x, tid = threadIdx.x;

    if (blk < NTOT) {
        int n = blk;
        for (int i = tid; i < 512; i += 256) smem[i] = W2[(size_t)n*512 + i];
        __syncthreads();
        if (n < HKC) {
            for (int np = tid; np < HKC; np += 256) {
                float s = 0.f;
                for (int t = 0; t < 512; t++) s += smem[t] * MqTd[t*NPAD + np];
                GT[(size_t)np*NPAD + n] = (bf16)(0.125f*s);
            }
        } else {
            for (int np = tid; np < HKM; np += 256) {
                float s = 0.f;
                for (int t = 0; t < 512; t++) s += smem[t] * MqTd[t*NPAD + HKC + np];
                GT[(size_t)(HKC+np)*NPAD + n] = (bf16)(0.125f*s);
            }
        }
    } else if (blk < 360) {
        int D0 = (blk - NTOT) * 8;
        for (int i = tid; i < 4096; i += 256)
            smem[i] = W_lin[(size_t)(D0 + (i >> 9))*512 + (i & 511)];
        __syncthreads();
        if (tid < NTOT) {
            float acc[8] = {};
            for (int d = 0; d < 512; d++) {
                float m = MqTd[d*NPAD + tid];
                #pragma unroll
                for (int r = 0; r < 8; r++) acc[r] += smem[r*512 + d] * m;
            }
            // K-tiled Bt: element (n=tid, k=D0+r) -> Bt[(step*256+n)*64 + off+r]
            int step = D0 >> 6, off = D0 & 63;
            #pragma unroll
            for (int r = 0; r < 8; r++)
                Bt[(size_t)(step*256 + tid)*64 + off + r] = (bf16)(0.125f*acc[r]);
        }
    } else {
        for (int i = tid; i < 512; i += 256) {
            smem[i] = b_lin[i];
            smem[512+i] = cbo[i];
            smem[1024+i] = mbo[i];
        }
        __syncthreads();
        if (tid < NTOT) {
            bool cult = tid < HKC;
            const float* bo_s = cult ? (smem+512) : (smem+1024);
            float sA = 0.f, sB = 0.f;
            for (int D = 0; D < 512; D++) {
                float m = MqTd[D*NPAD + tid];
                sA += smem[D]*m;
                sB += bo_s[D]*m;
            }
            float skq = 0.f;
            if (cult) {
                int h = tid / KC, k = tid % KC;
                for (int d = 0; d < 64; d++) skq += cbq[h*64+d] * k1c[k*512 + h*64 + d];
            } else {
                int nm = tid - HKC, h = nm / KM, k = nm % KM;
                for (int d = 0; d < 64; d++) skq += mbq[h*64+d] * k1m[k*512 + h*64 + d];
            }
            c1[tid] = 0.125f*(sA + skq);
            c2[tid] = 0.125f*(sB + skq);
        }
    }
}

// ================= g12: fused main pass, 64-row blocks, coalesced B =========
__global__ __launch_bounds__(256, 3) void g12_kernel(const float* __restrict__ emb,
                                                     const bf16* __restrict__ Bt,
                                                     const bf16* __restrict__ GT,
                                                     const float* __restrict__ c1,
                                                     const float* __restrict__ c2,
                                                     const float* __restrict__ mb,
                                                     float* __restrict__ A2)
{
    __shared__ union UU {
        struct { bf16 As[ROWS*72]; bf16 Bs[256*72]; } s;   // 9216 + 36864 B
        bf16 Ls[ROWS*264];                                 // 33792 B
    } u;
    __shared__ float bias1[256], bias2[256];
    const int tid = threadIdx.x;
    const int m0 = blockIdx.x*ROWS, b = blockIdx.x >> 5;
    bias1[tid] = c1[tid] + mb[b*NPAD + tid];
    bias2[tid] = c2[tid] + mb[b*NPAD + tid];
    const int wave = tid >> 6, lane = tid & 63, lr = lane & 15, kg = lane >> 4;
    floatx4 acc[4][4] = {};
    const int arow = tid >> 2, acol = (tid & 3)*16;
    const float* ap = emb + (size_t)(m0 + arow)*1024 + acol;
    bf16* asw = u.s.As + arow*72 + acol;
    // coalesced B staging: wave w, instr i covers tile elements
    // [w*4096 + i*512 + lane*8 .. +8) -> row n = w*64+i*8+(lane>>3), kk=(lane&7)*8
    const bf16* bp = Bt + (size_t)wave*4096 + lane*8;
    bf16* bsw = u.s.Bs + (size_t)(wave*64 + (lane >> 3))*72 + (lane & 7)*8;
    const bf16* afp = u.s.As + lr*72 + kg*8;
    const bf16* bfp = u.s.Bs + (wave*64 + lr)*72 + kg*8;

    // -------- phase 1: logits1 = emb @ Bt^T, pipelined K=64 steps --------
    float4 f0, f1, f2, f3;
    uint4 q0, q1, q2, q3, q4, q5, q6, q7;
    f0 = *(const float4*)(ap);      f1 = *(const float4*)(ap + 4);
    f2 = *(const float4*)(ap + 8);  f3 = *(const float4*)(ap + 12);
    q0 = *(const uint4*)(bp);        q1 = *(const uint4*)(bp + 512);
    q2 = *(const uint4*)(bp + 1024); q3 = *(const uint4*)(bp + 1536);
    q4 = *(const uint4*)(bp + 2048); q5 = *(const uint4*)(bp + 2560);
    q6 = *(const uint4*)(bp + 3072); q7 = *(const uint4*)(bp + 3584);
    #pragma unroll 1
    for (int t = 0; t < 16; t++) {
        asm volatile("s_waitcnt lgkmcnt(0)" ::: "memory");
        __builtin_amdgcn_s_barrier();          // prev frag reads done; LDS reusable
        // STAGE step t (vmcnt waits land here -- one iter after issue)
        {
            bf16x8 p0, p1;
            p0[0]=(bf16)f0.x; p0[1]=(bf16)f0.y; p0[2]=(bf16)f0.z; p0[3]=(bf16)f0.w;
            p0[4]=(bf16)f1.x; p0[5]=(bf16)f1.y; p0[6]=(bf16)f1.z; p0[7]=(bf16)f1.w;
            p1[0]=(bf16)f2.x; p1[1]=(bf16)f2.y; p1[2]=(bf16)f2.z; p1[3]=(bf16)f2.w;
            p1[4]=(bf16)f3.x; p1[5]=(bf16)f3.y; p1[6]=(bf16)f3.z; p1[7]=(bf16)f3.w;
            *(bf16x8*)asw = p0; *(bf16x8*)(asw + 8) = p1;
            *(uint4*)bsw = q0;          *(uint4*)(bsw + 576)  = q1;
            *(uint4*)(bsw + 1152) = q2; *(uint4*)(bsw + 1728) = q3;
            *(uint4*)(bsw + 2304) = q4; *(uint4*)(bsw + 2880) = q5;
            *(uint4*)(bsw + 3456) = q6; *(uint4*)(bsw + 4032) = q7;
        }
        // issue loads for step t+1 (stay in flight across barrier + MFMAs)
        if (t < 15) {
            const float* a2 = ap + (t + 1)*64;
            const bf16*  b2 = bp + (t + 1)*16384;
            f0 = *(const float4*)(a2);      f1 = *(const float4*)(a2 + 4);
            f2 = *(const float4*)(a2 + 8);  f3 = *(const float4*)(a2 + 12);
            q0 = *(const uint4*)(b2);        q1 = *(const uint4*)(b2 + 512);
            q2 = *(const uint4*)(b2 + 1024); q3 = *(const uint4*)(b2 + 1536);
            q4 = *(const uint4*)(b2 + 2048); q5 = *(const uint4*)(b2 + 2560);
            q6 = *(const uint4*)(b2 + 3072); q7 = *(const uint4*)(b2 + 3584);
        }
        asm volatile("s_waitcnt lgkmcnt(0)" ::: "memory");
        __builtin_amdgcn_s_barrier();          // staged tile visible
        #pragma unroll
        for (int kk = 0; kk < 64; kk += 32) {
            bf16x8 af[4], bfr[4];
            #pragma unroll
            for (int mi = 0; mi < 4; mi++) af[mi] = *(const bf16x8*)(afp + mi*16*72 + kk);
            #pragma unroll
            for (int nt = 0; nt < 4; nt++) bfr[nt] = *(const bf16x8*)(bfp + nt*16*72 + kk);
            #pragma unroll
            for (int mi = 0; mi < 4; mi++)
                #pragma unroll
                for (int nt = 0; nt < 4; nt++)
                    acc[mi][nt] = __builtin_amdgcn_mfma_f32_16x16x32_bf16(af[mi], bfr[nt], acc[mi][nt], 0, 0, 0);
        }
    }
    __syncthreads();
    // -------- epilogue 1: logits1 + bias -> Ls --------
    #pragma unroll
    for (int nt = 0; nt < 4; nt++) {
        int col = wave*64 + nt*16 + lr;
        float bb = bias1[col];
        #pragma unroll
        for (int mi = 0; mi < 4; mi++) {
            int row = mi*16 + kg*4;
            #pragma unroll
            for (int r = 0; r < 4; r++)
                u.Ls[(row + r)*264 + col] = (bf16)(acc[mi][nt][r] + bb);
        }
    }
    __syncthreads();
    // -------- softmax 1: 64 rows x 4 parts (per-head order unchanged) ------
    {
        int row = tid & 63, part = tid >> 6;
        bf16* Lr = u.Ls + row*264;
        if (part < 2) {
            for (int h = part*4; h < part*4 + 4; h++) {
                float lv[KC]; float m = -1e30f;
                #pragma unroll
                for (int j = 0; j < KC; j++) { lv[j] = (float)Lr[h*KC + j]; m = fmaxf(m, lv[j]); }
                float s = 0.f;
                #pragma unroll
                for (int j = 0; j < KC; j++) { lv[j] = __expf(lv[j] - m); s += lv[j]; }
                float inv = 1.f / s;
                #pragma unroll
                for (int j = 0; j < KC; j++) Lr[h*KC + j] = (bf16)(lv[j]*inv);
            }
        } else {
            for (int h = (part-2)*4; h < (part-2)*4 + 4; h++) {
                float lv[KM]; float m = -1e30f;
                #pragma unroll
                for (int j = 0; j < KM; j++) { lv[j] = (float)Lr[HKC + h*KM + j]; m = fmaxf(m, lv[j]); }
                float s = 0.f;
                #pragma unroll
                for (int j = 0; j < KM; j++) { lv[j] = __expf(lv[j] - m); s += lv[j]; }
                float inv = 1.f / s;
                #pragma unroll
                for (int j = 0; j < KM; j++) Lr[HKC + h*KM + j] = (bf16)(lv[j]*inv);
            }
            if (part == 3) for (int c = NTOT; c < NPAD; c++) Lr[c] = (bf16)0.f;
        }
    }
    __syncthreads();

    // -------- phase 3: logits2 = av1(Ls) @ GT^T, B direct from global/L2 ----
    floatx4 acc2[4][4] = {};
    {
        const bf16* afp3 = u.Ls + lr*264 + kg*8;
        const bf16* gt0 = GT + (size_t)(wave*64 + lr)*NPAD + kg*8;
        #pragma unroll 2
        for (int t = 0; t < 8; t++) {
            bf16x8 gbv[4], af3[4];
            #pragma unroll
            for (int nt = 0; nt < 4; nt++) gbv[nt] = *(const bf16x8*)(gt0 + nt*16*NPAD + t*32);
            #pragma unroll
            for (int mi = 0; mi < 4; mi++) af3[mi] = *(const bf16x8*)(afp3 + mi*16*264 + t*32);
            #pragma unroll
            for (int mi = 0; mi < 4; mi++)
                #pragma unroll
                for (int nt = 0; nt < 4; nt++)
                    acc2[mi][nt] = __builtin_amdgcn_mfma_f32_16x16x32_bf16(af3[mi], gbv[nt], acc2[mi][nt], 0, 0, 0);
        }
    }
    __syncthreads();   // all reads of av1 done before Ls is overwritten

    // -------- epilogue 2: logits2 + bias -> Ls --------
    #pragma unroll
    for (int nt = 0; nt < 4; nt++) {
        int col = wave*64 + nt*16 + lr;
        float bb = bias2[col];
        #pragma unroll
        for (int mi = 0; mi < 4; mi++) {
            int row = mi*16 + kg*4;
            #pragma unroll
            for (int r = 0; r < 4; r++)
                u.Ls[(row + r)*264 + col] = (bf16)(acc2[mi][nt][r] + bb);
        }
    }
    __syncthreads();
    // -------- softmax 2 --------
    {
        int row = tid & 63, part = tid >> 6;
        bf16* Lr = u.Ls + row*264;
        if (part < 2) {
            for (int h = part*4; h < part*4 + 4; h++) {
                float lv[KC]; float m = -1e30f;
                #pragma unroll
                for (int j = 0; j < KC; j++) { lv[j] = (float)Lr[h*KC + j]; m = fmaxf(m, lv[j]); }
                float s = 0.f;
                #pragma unroll
                for (int j = 0; j < KC; j++) { lv[j] = __expf(lv[j] - m); s += lv[j]; }
                float inv = 1.f / s;
                #pragma unroll
                for (int j = 0; j < KC; j++) Lr[h*KC + j] = (bf16)(lv[j]*inv);
            }
        } else {
            for (int h = (part-2)*4; h < (part-2)*4 + 4; h++) {
                float lv[KM]; float m = -1e30f;
                #pragma unroll
                for (int j = 0; j < KM; j++) { lv[j] = (float)Lr[HKC + h*KM + j]; m = fmaxf(m, lv[j]); }
                float s = 0.f;
                #pragma unroll
                for (int j = 0; j < KM; j++) { lv[j] = __expf(lv[j] - m); s += lv[j]; }
                float inv = 1.f / s;
                #pragma unroll
                for (int j = 0; j < KM; j++) Lr[HKC + h*KM + j] = (bf16)(lv[j]*inv);
            }
        }
    }
    __syncthreads();
    // -------- pool columns over 64 rows, accumulate into A2 --------
    {
        float s = 0.f;
        for (int r = 0; r < ROWS; r++) s += (float)u.Ls[r*264 + tid];
        if (tid < NTOT) atomicAdd(&A2[b*NPAD + tid], s);
    }
}

// ---------------- finalize ----------------
__global__ __launch_bounds__(256) void finalize_kernel(const float* __restrict__ A2, const float* __restrict__ W2,
                                                       const float* __restrict__ cbo, const float* __restrict__ mbo,
                                                       const float* __restrict__ P, float* __restrict__ out)
{
    __shared__ float a[NTOT];
    int b = blockIdx.x, tid = threadIdx.x;
    if (tid < NTOT) a[tid] = A2[b*NPAD + tid];
    __syncthreads();
    float invP = 1.f / P[b];
    for (int j = tid; j < 512; j += 256) {
        float pc = 2048.f*cbo[j], pm = 2048.f*mbo[j];
        for (int n = 0; n < HKC; n++) pc += a[n]*W2[n*512 + j];
        for (int n = HKC; n < NTOT; n++) pm += a[n]*W2[n*512 + j];
        out[b*512 + j] = pc*invP;
        out[BATCH*512 + b*512 + j] = (pc - pm)*invP;
    }
}

extern "C" void kernel_launch(void* const* d_in, const int* in_sizes, int n_in,
                              void* d_out, int out_size, void* d_ws, size_t ws_size,
                              hipStream_t stream)
{
    (void)in_sizes; (void)n_in; (void)out_size;
    const float* emb   = (const float*)d_in[0];
    const int* emask   = (const int*)d_in[1];
    const int* pmask   = (const int*)d_in[2];
    /* d_in[3] frame_mask: cancels in softmax */
    const int* cmask   = (const int*)d_in[4];
    const int* mmask   = (const int*)d_in[5];
    const float* W_lin = (const float*)d_in[6];
    const float* b_lin = (const float*)d_in[7];
    const float* ctab  = (const float*)d_in[8];
    const float* mtab  = (const float*)d_in[9];
    const float* cWq = (const float*)d_in[10]; const float* cbq = (const float*)d_in[11];
    const float* cWk = (const float*)d_in[12]; const float* cbk = (const float*)d_in[13];
    const float* cWv = (const float*)d_in[14]; const float* cbv = (const float*)d_in[15];
    const float* cWo = (const float*)d_in[16]; const float* cbo = (const float*)d_in[17];
    const float* mWq = (const float*)d_in[18]; const float* mbq = (const float*)d_in[19];
    const float* mWk = (const float*)d_in[20]; const float* mbk = (const float*)d_in[21];
    const float* mWv = (const float*)d_in[22]; const float* mbv = (const float*)d_in[23];
    const float* mWo = (const float*)d_in[24]; const float* mbo = (const float*)d_in[25];
    float* outp = (float*)d_out;

    if (ws_size < 40000000UL) return;

    char* ws = (char*)d_ws;
    size_t o = 0;
    bf16* Bt    = (bf16*)(ws + o); o += 256*1024*2;
    bf16* GT    = (bf16*)(ws + o); o += NPAD*NPAD*2;
    float* k1c  = (float*)(ws + o); o += KC*512*4;
    float* v1c  = (float*)(ws + o); o += KC*512*4;
    float* k1m  = (float*)(ws + o); o += KM*512*4;
    float* v1m  = (float*)(ws + o); o += KM*512*4;
    float* MqTd = (float*)(ws + o); o += (size_t)512*NPAD*4;
    float* W2   = (float*)(ws + o); o += (size_t)NTOT*512*4;
    float* c1   = (float*)(ws + o); o += NPAD*4;
    float* c2   = (float*)(ws + o); o += NPAD*4;
    float* mbt  = (float*)(ws + o); o += BATCH*NPAD*4;
    float* P    = (float*)(ws + o); o += 128;
    float* A2   = (float*)(ws + o); o += BATCH*NPAD*4;

    dim3 blk(256);

    prep1<<<dim3(65), blk, 0, stream>>>(emask, pmask, cmask, mmask, ctab, mtab,
                                        cWk, cbk, cWv, cbv, mWk, mbk, mWv, mbv,
                                        P, A2, mbt, k1c, v1c, k1m, v1m, GT, Bt, c1, c2);
    prep2<<<dim3(744), blk, 0, stream>>>(cWq, mWq, k1c, v1c, k1m, v1m, cWo, mWo, MqTd, W2);
    prep3<<<dim3(361), blk, 0, stream>>>(W_lin, b_lin, MqTd, W2, k1c, k1m,
                                         cbq, mbq, cbo, mbo, Bt, GT, c1, c2);
    g12_kernel<<<dim3(1024), blk, 0, stream>>>(emb, Bt, GT, c1, c2, mbt, A2);
    finalize_kernel<<<dim3(BATCH), blk, 0, stream>>>(A2, W2, cbo, mbo, P, outp);
}